// Round 9
// baseline (511.947 us; speedup 1.0000x reference)
//
#include <hip/hip_runtime.h>
#include <hip/hip_bf16.h>

// ---------------- problem constants ----------------
constexpr int NN = 100000;   // nodes
constexpr int NE = 3200000;  // edges
constexpr int CYC = 128;     // signal channels
constexpr int NB = 1563;     // buckets of 64 nodes: ceil(100000/64)
constexpr int EBLK = 256;    // edge-pass blocks
constexpr int ECHUNK = NE / EBLK;  // 12500
constexpr int MSCAN = NB * EBLK;   // 400128
constexpr int CAP = 2432;    // bucket edge capacity: mean 2048 + 8.5 sigma
constexpr int NBLK_A = (NN + 63) / 64;  // 1563 row-blocks for kA
constexpr int NCPAD = 100352;           // padded node-count table

// ---------------- workspace layout (bytes) ----------------
#define OFF_W1T    0u          // [512][128] bf16
#define OFF_W2T    131072u     // [16][512]  bf16
#define OFF_B1E    147456u     // [512] f32
#define OFF_SMALL  149504u     // 516 f32
#define OFF_W34    151808u     // [20][128] f32
#define OFF_B34    162048u     // [128] f32
#define OFF_FLAGS  162560u     // ints
#define OFF_XLB    163840u     // [N][32] bf16 (head0 @0..9, head1 @16..25) = 6,400,000
#define OFF_XR     6563840u    // [N][20] f32 = 8,000,000
#define OFF_NC     14563840u   // ncnt [100352] int = 401,408
#define OFF_GH     14965248u   // [NB][EBLK] int = 1,600,512
#define OFF_BB     16565760u   // [NB+1] int (pad 6400)
#define OFF_BS     16572160u   // scan block sums (196 ints, pad 1024)
#define OFF_BIN    16573184u   // [E] int2 = 25,600,000
// total = 42,173,184 bytes (< proven 51.4 MB)

// smallf float offsets
#define SF_WLR 0
#define SF_BLR 400
#define SF_ATT 440
#define SF_WE  460
#define SF_GB  480
#define SF_B2  500

typedef __attribute__((ext_vector_type(8))) short bf16x8;
typedef __attribute__((ext_vector_type(4))) float f32x4;

__device__ __forceinline__ float bfu(unsigned short x) {
  return __uint_as_float(((unsigned)x) << 16);
}
__device__ __forceinline__ short f2bf(float f) {
  __hip_bfloat16 h = __float2bfloat16(f);
  return *reinterpret_cast<short*>(&h);
}
__device__ __forceinline__ float LD(const void* p, long i, int f32f) {
  return f32f ? ((const float*)p)[i] : bfu(((const unsigned short*)p)[i]);
}

// ---------------- precompute + integrated dtype detect + ncnt zero ------------
__global__ __launch_bounds__(256) void kPrep(
    const void* __restrict__ W1, const void* __restrict__ b1,
    const void* __restrict__ gamma, const void* __restrict__ beta,
    const void* __restrict__ W2, const void* __restrict__ b2,
    const void* __restrict__ Wl, const void* __restrict__ bl,
    const void* __restrict__ Wr, const void* __restrict__ br,
    const void* __restrict__ We, const void* __restrict__ att,
    const void* __restrict__ gbias, const void* __restrict__ W3,
    const void* __restrict__ b3, const void* __restrict__ W4,
    const void* __restrict__ b4, const void* __restrict__ mask,
    int* __restrict__ flags,
    short* __restrict__ W1T, float* __restrict__ b1eff, short* __restrict__ W2T,
    float* __restrict__ smallf, float* __restrict__ W34, float* __restrict__ b34,
    int* __restrict__ ncnt)
{
  __shared__ int sfl[2];
  int t = threadIdx.x;
  if (t < 64) {
    const unsigned short* W1u = (const unsigned short*)W1;
    const unsigned* masku = (const unsigned*)mask;
    int big = 0;
#pragma unroll
    for (int k = 0; k < 8; k++) {
      unsigned e = (W1u[t * 8 + k] >> 7) & 0xFF;
      if (e >= 170) big++;
    }
    int byt = 0;
#pragma unroll
    for (int k = 0; k < 4; k++) if (masku[t * 4 + k] & ~1u) byt = 1;
#pragma unroll
    for (int o = 1; o < 64; o <<= 1) {
      big += __shfl_xor(big, o);
      byt |= __shfl_xor(byt, o);
    }
    if (t == 0) {
      sfl[0] = (big >= 4) ? 1 : 0;
      sfl[1] = byt;
      if (blockIdx.x == 0) { flags[0] = sfl[0]; flags[1] = byt; }
    }
  }
  __syncthreads();
  const int f32f = sfl[0];

  int tid = blockIdx.x * 256 + t;
  if (tid < NCPAD) ncnt[tid] = 0;

  const float rs = 0.999995000037f;  // 1/sqrt(1+1e-5)
  if (tid < 65536) {
    int j = tid >> 7, k = tid & 127;
    float s = LD(gamma, j, f32f) * rs;
    W1T[j * 128 + k] = f2bf(LD(W1, k * 512 + j, f32f) * s);
    if (k == 0) b1eff[j] = LD(b1, j, f32f) * s + LD(beta, j, f32f);
  } else if (tid < 73728) {
    int i = tid - 65536;
    int c = i >> 9, k = i & 511;
    W2T[c * 512 + k] = (c < 10) ? f2bf(LD(W2, k * 10 + c, f32f)) : (short)0;
  } else if (tid < 114688) {
    int i = tid - 73728;        // 16 threads per W34 output
    int o = i >> 4, k0 = i & 15;
    int j = o >> 7, tt = o & 127;
    float acc = 0.f;
    for (int k = k0; k < 512; k += 16)
      acc += LD(W3, j * 512 + k, f32f) * LD(W4, k * 128 + tt, f32f);
#pragma unroll
    for (int o2 = 1; o2 < 16; o2 <<= 1) acc += __shfl_xor(acc, o2);
    if (k0 == 0) W34[o] = acc;
  } else if (tid < 116736) {
    int i = tid - 114688;       // 16 threads per b34 output
    int tt = i >> 4, k0 = i & 15;
    float acc = 0.f;
    for (int k = k0; k < 512; k += 16)
      acc += LD(b3, k, f32f) * LD(W4, k * 128 + tt, f32f);
#pragma unroll
    for (int o2 = 1; o2 < 16; o2 <<= 1) acc += __shfl_xor(acc, o2);
    if (k0 == 0) b34[tt] = acc + LD(b4, tt, f32f);
  } else if (tid < 117252) {
    int i = tid - 116736;
    if (i < 400) {
      int c = i / 40, o = i % 40;
      smallf[SF_WLR + i] = (o < 20) ? LD(Wl, c * 20 + o, f32f) : LD(Wr, c * 20 + (o - 20), f32f);
    } else if (i < 440) {
      int o = i - 400;
      smallf[SF_BLR + o] = (o < 20) ? LD(bl, o, f32f) : LD(br, o - 20, f32f);
    } else if (i < 460) {
      smallf[SF_ATT + (i - 440)] = LD(att, i - 440, f32f);
    } else if (i < 480) {
      smallf[SF_WE + (i - 460)] = LD(We, i - 460, f32f);
    } else if (i < 500) {
      smallf[SF_GB + (i - 480)] = LD(gbias, i - 480, f32f);
    } else {
      int c = i - 500;
      smallf[SF_B2 + c] = (c < 10) ? LD(b2, c, f32f) : 0.f;
    }
  }
}

// ---------------- fused mlp_in + GAT linear transforms (round-7 proven) -------
// 64 rows/block, 4 waves each own 128 of the 512 cols.
// A-tile staged once in LDS; acc[4][8] -> 4 MFMA per B-load.
// Per-wave h1 buffer, TWO sequential 32-row halves, wave-local lgkmcnt sync.
// launch_bounds(256,2): VGPR cap 256 -> no spill. (Quarter-split r8: regression.)
__global__ __launch_bounds__(256, 2) void kA(
    const void* __restrict__ sig, const void* __restrict__ mask,
    const short* __restrict__ W1T, const float* __restrict__ b1eff,
    const short* __restrict__ W2T, const float* __restrict__ smallf,
    const int* __restrict__ flags,
    unsigned short* __restrict__ xlb, float* __restrict__ xr)
{
  // region R1 (17408 B) is time-multiplexed: A-tile -> xhp -> xlr (barriers between)
  __shared__ __align__(16) char sR1[17408];
  __shared__ short sH[4][32 * 136];   // per-wave h1 buffer [32][136] bf16
  __shared__ float sb1[512];
  __shared__ float sxh[64][12];
  __shared__ float sWlr[400];
  __shared__ float sblr[40];
  __shared__ float sb2[16];

  short (*sA)[136]        = (short (*)[136])sR1;       // 64*136*2 = 17408
  float (*sxhp)[64][17]   = (float (*)[64][17])sR1;    // 4*64*17*4 = 17408
  float (*sxlr)[40]       = (float (*)[40])sR1;        // 64*40*4  = 10240

  const int f32f = flags[0];
  const int mk8  = flags[1];
  int t = threadIdx.x;
  int w = t >> 6, l = t & 63;
  int lrow = l & 15, quad = l >> 4;
  int row0 = blockIdx.x * 64;

  for (int i = t; i < 512; i += 256) sb1[i] = b1eff[i];
  for (int i = t; i < 400; i += 256) sWlr[i] = smallf[SF_WLR + i];
  if (t < 40) sblr[t] = smallf[SF_BLR + t];
  if (t < 16) sb2[t] = smallf[SF_B2 + t];

  // ---- stage A tile: 64 rows x 128 bf16; 1024 16B-chunks, 4 per thread ----
  bf16x8 zz = {0, 0, 0, 0, 0, 0, 0, 0};
#pragma unroll
  for (int k = 0; k < 4; k++) {
    int idx = t + k * 256;
    int row = idx >> 4, seg = idx & 15;
    int gr = row0 + row;
    int grc = gr < NN ? gr : NN - 1;
    bool mbit = mk8 ? (((const unsigned char*)mask)[grc] != 0)
                    : (((const int*)mask)[grc] != 0);
    bf16x8 v;
    if (mbit) {
      v = zz;
    } else if (f32f) {
      const float4* Sf = (const float4*)((const float*)sig + (size_t)grc * CYC) + seg * 2;
      float4 x0 = Sf[0], x1 = Sf[1];
      v[0] = f2bf(x0.x); v[1] = f2bf(x0.y); v[2] = f2bf(x0.z); v[3] = f2bf(x0.w);
      v[4] = f2bf(x1.x); v[5] = f2bf(x1.y); v[6] = f2bf(x1.z); v[7] = f2bf(x1.w);
    } else {
      v = ((const bf16x8*)((const unsigned short*)sig + (size_t)grc * CYC))[seg];
    }
    *(bf16x8*)&sA[row][seg * 8] = v;
  }
  __syncthreads();

  // bias columns for this wave's 128 cols
  float bcol[8];
#pragma unroll
  for (int ct = 0; ct < 8; ct++) bcol[ct] = sb1[w * 128 + ct * 16 + lrow];

  // ---- GEMM1: 64 rows x 128 cols, K=128; 4 MFMA per bv load ----
  f32x4 acc[4][8];
#pragma unroll
  for (int rf = 0; rf < 4; rf++)
#pragma unroll
    for (int ct = 0; ct < 8; ct++) acc[rf][ct] = (f32x4){0.f, 0.f, 0.f, 0.f};

  const bf16x8* Bp = (const bf16x8*)W1T;
  int bvbase = w * 2048 + lrow * 16 + quad;
#pragma unroll
  for (int kt = 0; kt < 4; kt++) {
    bf16x8 a0 = *(const bf16x8*)&sA[lrow][kt * 32 + quad * 8];
    bf16x8 a1 = *(const bf16x8*)&sA[16 + lrow][kt * 32 + quad * 8];
    bf16x8 a2f = *(const bf16x8*)&sA[32 + lrow][kt * 32 + quad * 8];
    bf16x8 a3 = *(const bf16x8*)&sA[48 + lrow][kt * 32 + quad * 8];
#pragma unroll
    for (int ct = 0; ct < 8; ct++) {
      bf16x8 bv = Bp[bvbase + ct * 256 + kt * 4];
      acc[0][ct] = __builtin_amdgcn_mfma_f32_16x16x32_bf16(a0, bv, acc[0][ct], 0, 0, 0);
      acc[1][ct] = __builtin_amdgcn_mfma_f32_16x16x32_bf16(a1, bv, acc[1][ct], 0, 0, 0);
      acc[2][ct] = __builtin_amdgcn_mfma_f32_16x16x32_bf16(a2f, bv, acc[2][ct], 0, 0, 0);
      acc[3][ct] = __builtin_amdgcn_mfma_f32_16x16x32_bf16(a3, bv, acc[3][ct], 0, 0, 0);
    }
  }
  __syncthreads();   // all waves done reading sA -> R1 region free for xhp

  // GEMM2 B-operand (W2T) fragments, reused across both halves
  const bf16x8* B2p = (const bf16x8*)W2T;
  bf16x8 b2v[4];
#pragma unroll
  for (int kt2 = 0; kt2 < 4; kt2++) b2v[kt2] = B2p[lrow * 64 + w * 16 + kt2 * 4 + quad];

  short* hb = &sH[w][0];   // per-wave [32][136]
#pragma unroll
  for (int hf = 0; hf < 2; hf++) {
    // write h1 half (rows hf*32 .. hf*32+31) with bias + relu, bf16
#pragma unroll
    for (int rr = 0; rr < 2; rr++) {
      int rf = hf * 2 + rr;
#pragma unroll
      for (int ct = 0; ct < 8; ct++) {
        float bb = bcol[ct];
#pragma unroll
        for (int r = 0; r < 4; r++) {
          float vv = fmaxf(acc[rf][ct][r] + bb, 0.f);
          hb[(rr * 16 + quad * 4 + r) * 136 + ct * 16 + lrow] = f2bf(vv);
        }
      }
    }
    // wave-local fence: all our LDS writes retired before any lane reads them
    asm volatile("s_waitcnt lgkmcnt(0)" ::: "memory");

    // GEMM2 on this half: h1[32][128] @ W2T -> xh partial [32][16]
    f32x4 a2[2];
    a2[0] = (f32x4){0.f, 0.f, 0.f, 0.f};
    a2[1] = (f32x4){0.f, 0.f, 0.f, 0.f};
#pragma unroll
    for (int kt2 = 0; kt2 < 4; kt2++) {
      bf16x8 x0 = *(const bf16x8*)&hb[lrow * 136 + kt2 * 32 + quad * 8];
      bf16x8 x1 = *(const bf16x8*)&hb[(16 + lrow) * 136 + kt2 * 32 + quad * 8];
      a2[0] = __builtin_amdgcn_mfma_f32_16x16x32_bf16(x0, b2v[kt2], a2[0], 0, 0, 0);
      a2[1] = __builtin_amdgcn_mfma_f32_16x16x32_bf16(x1, b2v[kt2], a2[1], 0, 0, 0);
    }
#pragma unroll
    for (int f = 0; f < 2; f++)
#pragma unroll
      for (int r = 0; r < 4; r++)
        sxhp[w][hf * 32 + f * 16 + quad * 4 + r][lrow] = a2[f][r];
  }
  __syncthreads();

  // reduce 4 wave-partials -> xh[64][10] (+b2)
  for (int i = t; i < 640; i += 256) {
    int row = i / 10, c = i - row * 10;
    sxh[row][c] = sxhp[0][row][c] + sxhp[1][row][c] + sxhp[2][row][c] + sxhp[3][row][c] + sb2[c];
  }
  __syncthreads();

  // xl/xr into LDS staging (overlay on R1)
  for (int i = t; i < 2560; i += 256) {
    int row = i / 40, o = i - row * 40;
    float v = sblr[o];
#pragma unroll
    for (int c = 0; c < 10; c++) v += sxh[row][c] * sWlr[c * 40 + o];
    sxlr[row][o] = v;
  }
  __syncthreads();

  // coalesced stores
  int nrows = NN - row0; if (nrows > 64) nrows = 64;
  unsigned* xlb32 = (unsigned*)xlb;
#pragma unroll
  for (int k = 0; k < 4; k++) {
    int i = t + k * 256;
    int row = i >> 4, p = i & 15;
    if (row < nrows) {
      int s0 = 2 * p, s1 = 2 * p + 1;
      float lo = (s0 < 10) ? sxlr[row][s0] : (s0 >= 16 && s0 < 26) ? sxlr[row][s0 - 6] : 0.f;
      float hi = (s1 < 10) ? sxlr[row][s1] : (s1 >= 16 && s1 < 26) ? sxlr[row][s1 - 6] : 0.f;
      unsigned u = (unsigned)(unsigned short)f2bf(lo) |
                   ((unsigned)(unsigned short)f2bf(hi) << 16);
      xlb32[(size_t)(row0 + row) * 16 + p] = u;
    }
  }
#pragma unroll
  for (int k = 0; k < 5; k++) {
    int i = t + k * 256;
    int row = i / 20, c = i - row * 20;
    if (row < nrows) xr[(size_t)(row0 + row) * 20 + c] = sxlr[row][20 + c];
  }
}

// ---------------- CSR build stage 1: bucket histogram + global node histogram --
__global__ __launch_bounds__(256) void kB1(const int* __restrict__ ei,
                                           int* __restrict__ gh,
                                           int* __restrict__ ncnt) {
  __shared__ int h[NB];
  int t = threadIdx.x, blk = blockIdx.x;
  for (int i = t; i < NB; i += 256) h[i] = 0;
  __syncthreads();
  const int* dst = ei + NE;
  int base = blk * ECHUNK, bend = base + ECHUNK;
  for (int i = base + t; i < bend; i += 256) {
    int d = dst[i];
    atomicAdd(&h[d >> 6], 1);
    atomicAdd(&ncnt[d], 1);      // per-node count (L2-resident table)
  }
  __syncthreads();
  for (int i = t; i < NB; i += 256) gh[i * EBLK + blk] = h[i];
}

// ---------------- scan: per-block exclusive prefix (2048/block) ----------------
__global__ __launch_bounds__(256) void kS1(const int* __restrict__ in,
                                           int* __restrict__ outx,
                                           int* __restrict__ bsum, int nelem) {
  __shared__ int sS[256];
  int t = threadIdx.x;
  int base = blockIdx.x * 2048 + t * 8;
  int d[8], tsum = 0;
#pragma unroll
  for (int k = 0; k < 8; k++) {
    d[k] = (base + k < nelem) ? in[base + k] : 0;
    tsum += d[k];
  }
  sS[t] = tsum;
  __syncthreads();
  for (int o = 1; o < 256; o <<= 1) {
    int v = (t >= o) ? sS[t - o] : 0;
    __syncthreads();
    sS[t] += v;
    __syncthreads();
  }
  int run = sS[t] - tsum;
#pragma unroll
  for (int k = 0; k < 8; k++) {
    if (base + k < nelem) outx[base + k] = run;
    run += d[k];
  }
  if (t == 255) bsum[blockIdx.x] = sS[255];
}

__global__ __launch_bounds__(256) void kS2(int* __restrict__ bsum, int nb) {
  __shared__ int sS[256];
  int t = threadIdx.x;
  int v = (t < nb) ? bsum[t] : 0;
  sS[t] = v;
  __syncthreads();
  for (int o = 1; o < 256; o <<= 1) {
    int u = (t >= o) ? sS[t - o] : 0;
    __syncthreads();
    sS[t] += u;
    __syncthreads();
  }
  if (t < nb) bsum[t] = sS[t] - v;
}

__global__ __launch_bounds__(256) void kS3(int* __restrict__ gh,
                                           const int* __restrict__ bsum,
                                           int* __restrict__ bb) {
  int i = blockIdx.x * 256 + threadIdx.x;  // grid NB -> covers MSCAN exactly
  int v = gh[i] + bsum[i >> 11];
  gh[i] = v;
  if ((i & 255) == 0) bb[i >> 8] = v;
  if (i == 0) bb[NB] = NE;
}

// ---------------- bin edges by 64-node bucket (locality-friendly scatter) ------
__global__ __launch_bounds__(256) void kB3(const int* __restrict__ ei,
                                           const void* __restrict__ ew,
                                           const int* __restrict__ flags,
                                           const int* __restrict__ gh,
                                           int2* __restrict__ binned) {
  __shared__ int cur[NB];
  const int f32f = flags[0];
  int t = threadIdx.x, blk = blockIdx.x;
  for (int i = t; i < NB; i += 256) cur[i] = gh[i * EBLK + blk];
  __syncthreads();
  int base = blk * ECHUNK, bend = base + ECHUNK;
  for (int i = base + t; i < bend; i += 256) {
    int s = ei[i], d = ei[NE + i];
    float w = LD(ew, i, f32f);
    int b = d >> 6;
    int pos = atomicAdd(&cur[b], 1);
    binned[pos] = make_int2(s | ((d & 63) << 17), __float_as_int(w));
  }
}

// ---------------- fused per-bucket sort + aggregate + output GEMM ----------------
// one block per 64-node bucket; 512 threads; counts preloaded from ncnt ->
// single binned read (scatter only); 8 threads/node (2 head x 4 parity).
__global__ __launch_bounds__(512) void kAgg(
    const int* __restrict__ bb, const int2* __restrict__ binned,
    const int* __restrict__ ncnt,
    const unsigned short* __restrict__ xlb, const float* __restrict__ xr,
    const float* __restrict__ smallf, const float* __restrict__ W34,
    const float* __restrict__ b34, const int* __restrict__ flags,
    void* __restrict__ out)
{
  __shared__ int2  sES[CAP];        // 19,456 B (bucket edges, node-sorted)
  __shared__ float sXr[64 * 20];    // xr rows; reused for g after aggregate
  __shared__ float sW[2560];
  __shared__ float sb[128];
  __shared__ int   sCnt[64], sPre[64], sStart[64], sCur[64];
  __shared__ float sAtt[20], sWe[20], sGb[20];

  const int f32f = flags[0];
  int t = threadIdx.x, b = blockIdx.x;
  int node0 = b * 64;

  for (int i = t; i < 2560; i += 512) sW[i] = W34[i];
  for (int i = t; i < 1280; i += 512) {
    int gi = node0 * 20 + i;
    sXr[i] = (gi < NN * 20) ? xr[gi] : 0.f;
  }
  if (t < 128) sb[t] = b34[t];
  if (t < 64) sCnt[t] = ncnt[node0 + t];   // counts precomputed in kB1
  if (t < 20) { sAtt[t] = smallf[SF_ATT + t]; sWe[t] = smallf[SF_WE + t]; sGb[t] = smallf[SF_GB + t]; }
  __syncthreads();

  int base = bb[b], end = bb[b + 1];
  int ne = end - base;

  // 64-wide exclusive prefix over node counts
  if (t < 64) sPre[t] = sCnt[t];
  __syncthreads();
  for (int o = 1; o < 64; o <<= 1) {
    int v = 0;
    if (t < 64 && t >= o) v = sPre[t - o];
    __syncthreads();
    if (t < 64) sPre[t] += v;
    __syncthreads();
  }
  if (t < 64) {
    int ex = sPre[t] - sCnt[t];
    sStart[t] = ex;
    sCur[t] = ex;
  }
  __syncthreads();

  // single pass: scatter into node-sorted LDS order
  for (int i = t; i < ne; i += 512) {
    int2 e = binned[base + i];
    int dl = (unsigned)e.x >> 17;
    int pos = atomicAdd(&sCur[dl], 1);
    if (pos < CAP) sES[pos] = make_int2(e.x & 0x1FFFF, e.y);
  }
  __syncthreads();

  // aggregate: 8 threads/node = (head, 4-way parity)
  int n = t >> 3, sub = t & 7, head = sub >> 2, part = sub & 3;
  float xrw[10], attw[10], wew[10];
#pragma unroll
  for (int c = 0; c < 10; c++) {
    xrw[c]  = sXr[n * 20 + head * 10 + c];
    attw[c] = sAtt[head * 10 + c];
    wew[c]  = sWe[head * 10 + c];
  }
  float acc[10];
#pragma unroll
  for (int c = 0; c < 10; c++) acc[c] = 0.f;
  float den = 0.f;
  int s0 = sStart[n];
  int s1 = s0 + sCnt[n];
  if (s1 > CAP) s1 = CAP;  // statistically unreachable

  // 1-deep software pipeline on the xlb gather (edge records are LDS-fast)
  int i = s0 + part;
  int2 e; uint4 q; unsigned q4;
  if (i < s1) {
    e = sES[i];
    const unsigned short* p = xlb + (size_t)e.x * 32 + head * 16;
    q = *(const uint4*)p;
    q4 = *(const unsigned*)(p + 8);
  }
  while (i < s1) {
    int j = i + 4;
    int2 en; uint4 qn; unsigned qn4;
    if (j < s1) {
      en = sES[j];
      const unsigned short* pn = xlb + (size_t)en.x * 32 + head * 16;
      qn = *(const uint4*)pn;
      qn4 = *(const unsigned*)(pn + 8);
    }
    float vl[10];
    unsigned qq[5] = {q.x, q.y, q.z, q.w, q4};
#pragma unroll
    for (int k = 0; k < 5; k++) {
      vl[2 * k]     = __uint_as_float(qq[k] << 16);
      vl[2 * k + 1] = __uint_as_float(qq[k] & 0xffff0000u);
    }
    float ww = __int_as_float(e.y);
    float a = 0.f;
#pragma unroll
    for (int c = 0; c < 10; c++) {
      float v = vl[c] + xrw[c] + ww * wew[c];
      v = fmaxf(v, 0.2f * v);  // leaky_relu(0.2)
      a += v * attw[c];
    }
    float pp = __expf(a);
    den += pp;
#pragma unroll
    for (int c = 0; c < 10; c++) acc[c] += pp * vl[c];
    e = en; q = qn; q4 = qn4; i = j;
  }
  // combine 4-way parity group
  den += __shfl_xor(den, 1);
  den += __shfl_xor(den, 2);
#pragma unroll
  for (int c = 0; c < 10; c++) {
    acc[c] += __shfl_xor(acc[c], 1);
    acc[c] += __shfl_xor(acc[c], 2);
  }

  __syncthreads();  // xrw reads done; sXr reusable for g
  if (part == 0) {
    float inv = 1.f / (den + 1e-16f);
#pragma unroll
    for (int c = 0; c < 10; c++)
      sXr[n * 20 + head * 10 + c] = acc[c] * inv + sGb[head * 10 + c];
  }
  __syncthreads();

  // output: out[node] = g @ W34 + b34 ; 4 node-groups in parallel
  int col = t & 127, grp = t >> 7;
  for (int n2 = grp; n2 < 64; n2 += 4) {
    int gn = node0 + n2;
    if (gn >= NN) break;
    float v = sb[col];
    const float* g = &sXr[n2 * 20];
#pragma unroll
    for (int c = 0; c < 20; c++) v += g[c] * sW[c * 128 + col];
    if (f32f) ((float*)out)[(size_t)gn * 128 + col] = v;
    else ((unsigned short*)out)[(size_t)gn * 128 + col] = (unsigned short)f2bf(v);
  }
}

extern "C" void kernel_launch(void* const* d_in, const int* in_sizes, int n_in,
                              void* d_out, int out_size, void* d_ws, size_t ws_size,
                              hipStream_t stream) {
  (void)in_sizes; (void)n_in; (void)out_size; (void)ws_size;
  const void* sig  = d_in[0];
  const int*  ei   = (const int*)d_in[1];
  const void* ew   = d_in[2];
  const void* mask = d_in[3];
  const void* W1   = d_in[4];
  const void* b1   = d_in[5];
  const void* gam  = d_in[6];
  const void* bet  = d_in[7];
  const void* W2   = d_in[8];
  const void* b2   = d_in[9];
  const void* Wl   = d_in[10];
  const void* bl   = d_in[11];
  const void* Wr   = d_in[12];
  const void* br   = d_in[13];
  const void* We   = d_in[14];
  const void* att  = d_in[15];
  const void* gb   = d_in[16];
  const void* W3   = d_in[17];
  const void* b3   = d_in[18];
  const void* W4   = d_in[19];
  const void* b4   = d_in[20];

  char* ws = (char*)d_ws;
  short* W1T    = (short*)(ws + OFF_W1T);
  short* W2T    = (short*)(ws + OFF_W2T);
  float* b1eff  = (float*)(ws + OFF_B1E);
  float* smallf = (float*)(ws + OFF_SMALL);
  float* W34    = (float*)(ws + OFF_W34);
  float* b34    = (float*)(ws + OFF_B34);
  int*   flags  = (int*)(ws + OFF_FLAGS);
  unsigned short* xlb = (unsigned short*)(ws + OFF_XLB);
  float* xr     = (float*)(ws + OFF_XR);
  int*   ncnt   = (int*)(ws + OFF_NC);
  int*   gh     = (int*)(ws + OFF_GH);
  int*   bb     = (int*)(ws + OFF_BB);
  int*   bsum   = (int*)(ws + OFF_BS);
  int2*  bincsr = (int2*)(ws + OFF_BIN);

  kPrep<<<459, 256, 0, stream>>>(W1, b1, gam, bet, W2, b2, Wl, bl, Wr, br, We, att,
                                 gb, W3, b3, W4, b4, mask, flags,
                                 W1T, b1eff, W2T, smallf, W34, b34, ncnt);
  kA<<<NBLK_A, 256, 0, stream>>>(sig, mask, W1T, b1eff, W2T, smallf, flags, xlb, xr);
  kB1<<<EBLK, 256, 0, stream>>>(ei, gh, ncnt);
  kS1<<<(MSCAN + 2047) / 2048, 256, 0, stream>>>(gh, gh, bsum, MSCAN);
  kS2<<<1, 256, 0, stream>>>(bsum, (MSCAN + 2047) / 2048);
  kS3<<<NB, 256, 0, stream>>>(gh, bsum, bb);
  kB3<<<EBLK, 256, 0, stream>>>(ei, ew, flags, gh, bincsr);
  kAgg<<<NB, 512, 0, stream>>>(bb, bincsr, ncnt, xlb, xr, smallf, W34, b34, flags, d_out);
}

// Round 10
// 404.686 us; speedup vs baseline: 1.2650x; 1.2650x over previous
//
#include <hip/hip_runtime.h>
#include <hip/hip_bf16.h>

// ---------------- problem constants ----------------
constexpr int NN = 100000;   // nodes
constexpr int NE = 3200000;  // edges
constexpr int CYC = 128;     // signal channels
constexpr int NB = 1563;     // buckets of 64 nodes: ceil(100000/64)
constexpr int EBLK = 256;    // edge-pass blocks
constexpr int ECHUNK = NE / EBLK;  // 12500
constexpr int MSCAN = NB * EBLK;   // 400128
constexpr int CAP = 2432;    // bucket edge capacity: mean 2048 + 8.5 sigma
constexpr int NBLK_A = NN / 32;    // 3125 row-blocks for kA (32 rows each, exact)

// ---------------- workspace layout (bytes) ----------------
#define OFF_W1T    0u          // [512][128] bf16
#define OFF_W2T    131072u     // [16][512]  bf16
#define OFF_B1E    147456u     // [512] f32
#define OFF_SMALL  149504u     // 516 f32
#define OFF_W34    151808u     // [20][128] f32
#define OFF_B34    162048u     // [128] f32
#define OFF_FLAGS  162560u     // ints
#define OFF_XLB    163840u     // [N][32] bf16 (head0 @0..9, head1 @16..25) = 6,400,000
#define OFF_XR     6563840u    // [N][20] f32 = 8,000,000
#define OFF_GH     14965248u   // [NB][EBLK] int = 1,600,512
#define OFF_BB     16565760u   // [NB+1] int (pad 6400)
#define OFF_BS     16572160u   // scan block sums (196 ints, pad 1024)
#define OFF_BIN    16573184u   // [E] int2 = 25,600,000
// total = 42,173,184 bytes (< proven 51.4 MB)

// smallf float offsets
#define SF_WLR 0
#define SF_BLR 400
#define SF_ATT 440
#define SF_WE  460
#define SF_GB  480
#define SF_B2  500

typedef __attribute__((ext_vector_type(8))) short bf16x8;
typedef __attribute__((ext_vector_type(4))) float f32x4;

__device__ __forceinline__ float bfu(unsigned short x) {
  return __uint_as_float(((unsigned)x) << 16);
}
__device__ __forceinline__ short f2bf(float f) {
  __hip_bfloat16 h = __float2bfloat16(f);
  return *reinterpret_cast<short*>(&h);
}
__device__ __forceinline__ float LD(const void* p, long i, int f32f) {
  return f32f ? ((const float*)p)[i] : bfu(((const unsigned short*)p)[i]);
}

// ---------------- precompute + integrated dtype detect ----------------
// W34/b34 use 16 threads per output + shfl reduce (512-deep dot -> 32 iters/lane)
__global__ __launch_bounds__(256) void kPrep(
    const void* __restrict__ W1, const void* __restrict__ b1,
    const void* __restrict__ gamma, const void* __restrict__ beta,
    const void* __restrict__ W2, const void* __restrict__ b2,
    const void* __restrict__ Wl, const void* __restrict__ bl,
    const void* __restrict__ Wr, const void* __restrict__ br,
    const void* __restrict__ We, const void* __restrict__ att,
    const void* __restrict__ gbias, const void* __restrict__ W3,
    const void* __restrict__ b3, const void* __restrict__ W4,
    const void* __restrict__ b4, const void* __restrict__ mask,
    int* __restrict__ flags,
    short* __restrict__ W1T, float* __restrict__ b1eff, short* __restrict__ W2T,
    float* __restrict__ smallf, float* __restrict__ W34, float* __restrict__ b34)
{
  __shared__ int sfl[2];
  int t = threadIdx.x;
  if (t < 64) {
    const unsigned short* W1u = (const unsigned short*)W1;
    const unsigned* masku = (const unsigned*)mask;
    int big = 0;
#pragma unroll
    for (int k = 0; k < 8; k++) {
      unsigned e = (W1u[t * 8 + k] >> 7) & 0xFF;
      if (e >= 170) big++;
    }
    int byt = 0;
#pragma unroll
    for (int k = 0; k < 4; k++) if (masku[t * 4 + k] & ~1u) byt = 1;
#pragma unroll
    for (int o = 1; o < 64; o <<= 1) {
      big += __shfl_xor(big, o);
      byt |= __shfl_xor(byt, o);
    }
    if (t == 0) {
      sfl[0] = (big >= 4) ? 1 : 0;
      sfl[1] = byt;
      if (blockIdx.x == 0) { flags[0] = sfl[0]; flags[1] = byt; }
    }
  }
  __syncthreads();
  const int f32f = sfl[0];

  int tid = blockIdx.x * 256 + t;
  const float rs = 0.999995000037f;  // 1/sqrt(1+1e-5)
  if (tid < 65536) {
    int j = tid >> 7, k = tid & 127;
    float s = LD(gamma, j, f32f) * rs;
    W1T[j * 128 + k] = f2bf(LD(W1, k * 512 + j, f32f) * s);
    if (k == 0) b1eff[j] = LD(b1, j, f32f) * s + LD(beta, j, f32f);
  } else if (tid < 73728) {
    int i = tid - 65536;
    int c = i >> 9, k = i & 511;
    W2T[c * 512 + k] = (c < 10) ? f2bf(LD(W2, k * 10 + c, f32f)) : (short)0;
  } else if (tid < 114688) {
    int i = tid - 73728;        // 16 threads per W34 output
    int o = i >> 4, k0 = i & 15;
    int j = o >> 7, tt = o & 127;
    float acc = 0.f;
    for (int k = k0; k < 512; k += 16)
      acc += LD(W3, j * 512 + k, f32f) * LD(W4, k * 128 + tt, f32f);
#pragma unroll
    for (int o2 = 1; o2 < 16; o2 <<= 1) acc += __shfl_xor(acc, o2);
    if (k0 == 0) W34[o] = acc;
  } else if (tid < 116736) {
    int i = tid - 114688;       // 16 threads per b34 output
    int tt = i >> 4, k0 = i & 15;
    float acc = 0.f;
    for (int k = k0; k < 512; k += 16)
      acc += LD(b3, k, f32f) * LD(W4, k * 128 + tt, f32f);
#pragma unroll
    for (int o2 = 1; o2 < 16; o2 <<= 1) acc += __shfl_xor(acc, o2);
    if (k0 == 0) b34[tt] = acc + LD(b4, tt, f32f);
  } else if (tid < 117252) {
    int i = tid - 116736;
    if (i < 400) {
      int c = i / 40, o = i % 40;
      smallf[SF_WLR + i] = (o < 20) ? LD(Wl, c * 20 + o, f32f) : LD(Wr, c * 20 + (o - 20), f32f);
    } else if (i < 440) {
      int o = i - 400;
      smallf[SF_BLR + o] = (o < 20) ? LD(bl, o, f32f) : LD(br, o - 20, f32f);
    } else if (i < 460) {
      smallf[SF_ATT + (i - 440)] = LD(att, i - 440, f32f);
    } else if (i < 480) {
      smallf[SF_WE + (i - 460)] = LD(We, i - 460, f32f);
    } else if (i < 500) {
      smallf[SF_GB + (i - 480)] = LD(gbias, i - 480, f32f);
    } else {
      int c = i - 500;
      smallf[SF_B2 + c] = (c < 10) ? LD(b2, c, f32f) : 0.f;
    }
  }
}

// ---------------- fused mlp_in + GAT linear transforms (32-row, low-reg) -------
// 32 rows/block, 4 waves each own 128 of the 512 cols; grid 3125.
// acc[2][8] = 64 AGPR -> total regs ~150 -> 3 waves/SIMD at (256,3)
// (r0 precedent: same geometry measured VGPR=84, no spill, 28% occupancy).
// A-tile staged ONCE in shared LDS; h1 in two 16-row halves (r8-verified body);
// coalesced stores. LDS ~31.5KB -> 3 blocks/CU (register-limited).
__global__ __launch_bounds__(256, 3) void kA(
    const void* __restrict__ sig, const void* __restrict__ mask,
    const short* __restrict__ W1T, const float* __restrict__ b1eff,
    const short* __restrict__ W2T, const float* __restrict__ smallf,
    const int* __restrict__ flags,
    unsigned short* __restrict__ xlb, float* __restrict__ xr)
{
  // region R1 (8704 B) time-multiplexed: A-tile -> xhp -> xlr (barriers between)
  __shared__ __align__(16) char sR1[8704];
  __shared__ short sH[4][16 * 136];   // per-wave h1 half buffer [16][136] bf16
  __shared__ float sb1[512];
  __shared__ float sxh[32][12];
  __shared__ float sWlr[400];
  __shared__ float sblr[40];
  __shared__ float sb2[16];

  short (*sA)[136]        = (short (*)[136])sR1;       // 32*136*2 = 8704
  float (*sxhp)[32][17]   = (float (*)[32][17])sR1;    // 4*32*17*4 = 8704
  float (*sxlr)[40]       = (float (*)[40])sR1;        // 32*40*4  = 5120

  const int f32f = flags[0];
  const int mk8  = flags[1];
  int t = threadIdx.x;
  int w = t >> 6, l = t & 63;
  int lrow = l & 15, quad = l >> 4;
  int row0 = blockIdx.x * 32;

  for (int i = t; i < 512; i += 256) sb1[i] = b1eff[i];
  for (int i = t; i < 400; i += 256) sWlr[i] = smallf[SF_WLR + i];
  if (t < 40) sblr[t] = smallf[SF_BLR + t];
  if (t < 16) sb2[t] = smallf[SF_B2 + t];

  // ---- stage A tile: 32 rows x 128 bf16; 512 16B-chunks, 2 per thread ----
  bf16x8 zz = {0, 0, 0, 0, 0, 0, 0, 0};
#pragma unroll
  for (int k = 0; k < 2; k++) {
    int idx = t + k * 256;
    int row = idx >> 4, seg = idx & 15;
    int gr = row0 + row;
    int grc = gr < NN ? gr : NN - 1;
    bool mbit = mk8 ? (((const unsigned char*)mask)[grc] != 0)
                    : (((const int*)mask)[grc] != 0);
    bf16x8 v;
    if (mbit) {
      v = zz;
    } else if (f32f) {
      const float4* Sf = (const float4*)((const float*)sig + (size_t)grc * CYC) + seg * 2;
      float4 x0 = Sf[0], x1 = Sf[1];
      v[0] = f2bf(x0.x); v[1] = f2bf(x0.y); v[2] = f2bf(x0.z); v[3] = f2bf(x0.w);
      v[4] = f2bf(x1.x); v[5] = f2bf(x1.y); v[6] = f2bf(x1.z); v[7] = f2bf(x1.w);
    } else {
      v = ((const bf16x8*)((const unsigned short*)sig + (size_t)grc * CYC))[seg];
    }
    *(bf16x8*)&sA[row][seg * 8] = v;
  }
  __syncthreads();

  // bias columns for this wave's 128 cols
  float bcol[8];
#pragma unroll
  for (int ct = 0; ct < 8; ct++) bcol[ct] = sb1[w * 128 + ct * 16 + lrow];

  // ---- GEMM1: 32 rows x 128 cols, K=128; acc[2][8] = 64 AGPR ----
  f32x4 acc[2][8];
#pragma unroll
  for (int rf = 0; rf < 2; rf++)
#pragma unroll
    for (int ct = 0; ct < 8; ct++) acc[rf][ct] = (f32x4){0.f, 0.f, 0.f, 0.f};

  const bf16x8* Bp = (const bf16x8*)W1T;
  int bvbase = w * 2048 + lrow * 16 + quad;
#pragma unroll
  for (int kt = 0; kt < 4; kt++) {
    bf16x8 a0 = *(const bf16x8*)&sA[lrow][kt * 32 + quad * 8];
    bf16x8 a1 = *(const bf16x8*)&sA[16 + lrow][kt * 32 + quad * 8];
#pragma unroll
    for (int ct = 0; ct < 8; ct++) {
      bf16x8 bv = Bp[bvbase + ct * 256 + kt * 4];
      acc[0][ct] = __builtin_amdgcn_mfma_f32_16x16x32_bf16(a0, bv, acc[0][ct], 0, 0, 0);
      acc[1][ct] = __builtin_amdgcn_mfma_f32_16x16x32_bf16(a1, bv, acc[1][ct], 0, 0, 0);
    }
  }
  __syncthreads();   // all waves done reading sA -> R1 region free for xhp

  // GEMM2 B-operand (W2T) fragments, reused across both halves
  const bf16x8* B2p = (const bf16x8*)W2T;
  bf16x8 b2v[4];
#pragma unroll
  for (int kt2 = 0; kt2 < 4; kt2++) b2v[kt2] = B2p[lrow * 64 + w * 16 + kt2 * 4 + quad];

  short* hb = &sH[w][0];   // per-wave [16][136]
#pragma unroll
  for (int hf = 0; hf < 2; hf++) {
    // write h1 half (rows hf*16 .. hf*16+15) with bias + relu, bf16
#pragma unroll
    for (int ct = 0; ct < 8; ct++) {
      float bb = bcol[ct];
#pragma unroll
      for (int r = 0; r < 4; r++) {
        float vv = fmaxf(acc[hf][ct][r] + bb, 0.f);
        hb[(quad * 4 + r) * 136 + ct * 16 + lrow] = f2bf(vv);
      }
    }
    // wave-local fence: all our LDS writes retired before any lane reads them
    asm volatile("s_waitcnt lgkmcnt(0)" ::: "memory");

    // GEMM2 on this half: h1[16][128] @ W2T -> xh partial [16][16]
    f32x4 a2 = (f32x4){0.f, 0.f, 0.f, 0.f};
#pragma unroll
    for (int kt2 = 0; kt2 < 4; kt2++) {
      bf16x8 x0 = *(const bf16x8*)&hb[lrow * 136 + kt2 * 32 + quad * 8];
      a2 = __builtin_amdgcn_mfma_f32_16x16x32_bf16(x0, b2v[kt2], a2, 0, 0, 0);
    }
#pragma unroll
    for (int r = 0; r < 4; r++)
      sxhp[w][hf * 16 + quad * 4 + r][lrow] = a2[r];
  }
  __syncthreads();

  // reduce 4 wave-partials -> xh[32][10] (+b2)
  for (int i = t; i < 320; i += 256) {
    int row = i / 10, c = i - row * 10;
    sxh[row][c] = sxhp[0][row][c] + sxhp[1][row][c] + sxhp[2][row][c] + sxhp[3][row][c] + sb2[c];
  }
  __syncthreads();

  // xl/xr into LDS staging (overlay on R1)
  for (int i = t; i < 1280; i += 256) {
    int row = i / 40, o = i - row * 40;
    float v = sblr[o];
#pragma unroll
    for (int c = 0; c < 10; c++) v += sxh[row][c] * sWlr[c * 40 + o];
    sxlr[row][o] = v;
  }
  __syncthreads();

  // coalesced stores (nrows always 32: NN = 3125*32 exact)
  unsigned* xlb32 = (unsigned*)xlb;
#pragma unroll
  for (int k = 0; k < 2; k++) {
    int i = t + k * 256;
    int row = i >> 4, p = i & 15;
    int s0 = 2 * p, s1 = 2 * p + 1;
    float lo = (s0 < 10) ? sxlr[row][s0] : (s0 >= 16 && s0 < 26) ? sxlr[row][s0 - 6] : 0.f;
    float hi = (s1 < 10) ? sxlr[row][s1] : (s1 >= 16 && s1 < 26) ? sxlr[row][s1 - 6] : 0.f;
    unsigned u = (unsigned)(unsigned short)f2bf(lo) |
                 ((unsigned)(unsigned short)f2bf(hi) << 16);
    xlb32[(size_t)(row0 + row) * 16 + p] = u;
  }
#pragma unroll
  for (int k = 0; k < 3; k++) {
    int i = t + k * 256;
    if (i < 640) {
      int row = i / 20, c = i - row * 20;
      xr[(size_t)(row0 + row) * 20 + c] = sxlr[row][20 + c];
    }
  }
}

// ---------------- CSR build stage 1: per-block bucket histogram ----------------
__global__ __launch_bounds__(256) void kB1(const int* __restrict__ ei,
                                           int* __restrict__ gh) {
  __shared__ int h[NB];
  int t = threadIdx.x, blk = blockIdx.x;
  for (int i = t; i < NB; i += 256) h[i] = 0;
  __syncthreads();
  const int* dst = ei + NE;
  int base = blk * ECHUNK, bend = base + ECHUNK;
  for (int i = base + t; i < bend; i += 256)
    atomicAdd(&h[dst[i] >> 6], 1);
  __syncthreads();
  for (int i = t; i < NB; i += 256) gh[i * EBLK + blk] = h[i];
}

// ---------------- scan: per-block exclusive prefix (2048/block) ----------------
__global__ __launch_bounds__(256) void kS1(const int* __restrict__ in,
                                           int* __restrict__ outx,
                                           int* __restrict__ bsum, int nelem) {
  __shared__ int sS[256];
  int t = threadIdx.x;
  int base = blockIdx.x * 2048 + t * 8;
  int d[8], tsum = 0;
#pragma unroll
  for (int k = 0; k < 8; k++) {
    d[k] = (base + k < nelem) ? in[base + k] : 0;
    tsum += d[k];
  }
  sS[t] = tsum;
  __syncthreads();
  for (int o = 1; o < 256; o <<= 1) {
    int v = (t >= o) ? sS[t - o] : 0;
    __syncthreads();
    sS[t] += v;
    __syncthreads();
  }
  int run = sS[t] - tsum;
#pragma unroll
  for (int k = 0; k < 8; k++) {
    if (base + k < nelem) outx[base + k] = run;
    run += d[k];
  }
  if (t == 255) bsum[blockIdx.x] = sS[255];
}

__global__ __launch_bounds__(256) void kS2(int* __restrict__ bsum, int nb) {
  __shared__ int sS[256];
  int t = threadIdx.x;
  int v = (t < nb) ? bsum[t] : 0;
  sS[t] = v;
  __syncthreads();
  for (int o = 1; o < 256; o <<= 1) {
    int u = (t >= o) ? sS[t - o] : 0;
    __syncthreads();
    sS[t] += u;
    __syncthreads();
  }
  if (t < nb) bsum[t] = sS[t] - v;
}

__global__ __launch_bounds__(256) void kS3(int* __restrict__ gh,
                                           const int* __restrict__ bsum,
                                           int* __restrict__ bb) {
  int i = blockIdx.x * 256 + threadIdx.x;  // grid NB -> covers MSCAN exactly
  int v = gh[i] + bsum[i >> 11];
  gh[i] = v;
  if ((i & 255) == 0) bb[i >> 8] = v;
  if (i == 0) bb[NB] = NE;
}

// ---------------- bin edges by 64-node bucket (locality-friendly scatter) ------
__global__ __launch_bounds__(256) void kB3(const int* __restrict__ ei,
                                           const void* __restrict__ ew,
                                           const int* __restrict__ flags,
                                           const int* __restrict__ gh,
                                           int2* __restrict__ binned) {
  __shared__ int cur[NB];
  const int f32f = flags[0];
  int t = threadIdx.x, blk = blockIdx.x;
  for (int i = t; i < NB; i += 256) cur[i] = gh[i * EBLK + blk];
  __syncthreads();
  int base = blk * ECHUNK, bend = base + ECHUNK;
  for (int i = base + t; i < bend; i += 256) {
    int s = ei[i], d = ei[NE + i];
    float w = LD(ew, i, f32f);
    int b = d >> 6;
    int pos = atomicAdd(&cur[b], 1);
    binned[pos] = make_int2(s | ((d & 63) << 17), __float_as_int(w));
  }
}

// ---------------- fused per-bucket sort + aggregate + output GEMM ----------------
// one block per 64-node bucket; 512 threads; LDS counting sort (count from
// global, scatter via L2-hot re-read into sES); 8 threads/node (2 head x 4 par).
__global__ __launch_bounds__(512) void kAgg(
    const int* __restrict__ bb, const int2* __restrict__ binned,
    const unsigned short* __restrict__ xlb, const float* __restrict__ xr,
    const float* __restrict__ smallf, const float* __restrict__ W34,
    const float* __restrict__ b34, const int* __restrict__ flags,
    void* __restrict__ out)
{
  __shared__ int2  sES[CAP];        // 19,456 B (bucket edges, node-sorted)
  __shared__ float sXr[64 * 20];    // xr rows; reused for g after aggregate
  __shared__ float sW[2560];
  __shared__ float sb[128];
  __shared__ int   sCnt[64], sPre[64], sStart[64], sCur[64];
  __shared__ float sAtt[20], sWe[20], sGb[20];

  const int f32f = flags[0];
  int t = threadIdx.x, b = blockIdx.x;
  int node0 = b * 64;

  for (int i = t; i < 2560; i += 512) sW[i] = W34[i];
  for (int i = t; i < 1280; i += 512) {
    int gi = node0 * 20 + i;
    sXr[i] = (gi < NN * 20) ? xr[gi] : 0.f;
  }
  if (t < 128) sb[t] = b34[t];
  if (t < 64) sCnt[t] = 0;
  if (t < 20) { sAtt[t] = smallf[SF_ATT + t]; sWe[t] = smallf[SF_WE + t]; sGb[t] = smallf[SF_GB + t]; }
  __syncthreads();

  int base = bb[b], end = bb[b + 1];
  int ne = end - base;

  // pass 1: count per local node
  for (int i = t; i < ne; i += 512)
    atomicAdd(&sCnt[(unsigned)binned[base + i].x >> 17], 1);
  __syncthreads();

  // 64-wide exclusive prefix
  if (t < 64) sPre[t] = sCnt[t];
  __syncthreads();
  for (int o = 1; o < 64; o <<= 1) {
    int v = 0;
    if (t < 64 && t >= o) v = sPre[t - o];
    __syncthreads();
    if (t < 64) sPre[t] += v;
    __syncthreads();
  }
  if (t < 64) {
    int ex = sPre[t] - sCnt[t];
    sStart[t] = ex;
    sCur[t] = ex;
  }
  __syncthreads();

  // pass 2: scatter into node-sorted LDS order (re-read is L2-hot)
  for (int i = t; i < ne; i += 512) {
    int2 e = binned[base + i];
    int dl = (unsigned)e.x >> 17;
    int pos = atomicAdd(&sCur[dl], 1);
    if (pos < CAP) sES[pos] = make_int2(e.x & 0x1FFFF, e.y);
  }
  __syncthreads();

  // aggregate: 8 threads/node = (head, 4-way parity)
  int n = t >> 3, sub = t & 7, head = sub >> 2, part = sub & 3;
  float xrw[10], attw[10], wew[10];
#pragma unroll
  for (int c = 0; c < 10; c++) {
    xrw[c]  = sXr[n * 20 + head * 10 + c];
    attw[c] = sAtt[head * 10 + c];
    wew[c]  = sWe[head * 10 + c];
  }
  float acc[10];
#pragma unroll
  for (int c = 0; c < 10; c++) acc[c] = 0.f;
  float den = 0.f;
  int s0 = sStart[n];
  int s1 = s0 + sCnt[n];
  if (s1 > CAP) s1 = CAP;  // statistically unreachable

  // 1-deep software pipeline on the xlb gather (edge records are LDS-fast)
  int i = s0 + part;
  int2 e; uint4 q; unsigned q4;
  if (i < s1) {
    e = sES[i];
    const unsigned short* p = xlb + (size_t)e.x * 32 + head * 16;
    q = *(const uint4*)p;
    q4 = *(const unsigned*)(p + 8);
  }
  while (i < s1) {
    int j = i + 4;
    int2 en; uint4 qn; unsigned qn4;
    if (j < s1) {
      en = sES[j];
      const unsigned short* pn = xlb + (size_t)en.x * 32 + head * 16;
      qn = *(const uint4*)pn;
      qn4 = *(const unsigned*)(pn + 8);
    }
    float vl[10];
    unsigned qq[5] = {q.x, q.y, q.z, q.w, q4};
#pragma unroll
    for (int k = 0; k < 5; k++) {
      vl[2 * k]     = __uint_as_float(qq[k] << 16);
      vl[2 * k + 1] = __uint_as_float(qq[k] & 0xffff0000u);
    }
    float ww = __int_as_float(e.y);
    float a = 0.f;
#pragma unroll
    for (int c = 0; c < 10; c++) {
      float v = vl[c] + xrw[c] + ww * wew[c];
      v = fmaxf(v, 0.2f * v);  // leaky_relu(0.2)
      a += v * attw[c];
    }
    float pp = __expf(a);
    den += pp;
#pragma unroll
    for (int c = 0; c < 10; c++) acc[c] += pp * vl[c];
    e = en; q = qn; q4 = qn4; i = j;
  }
  // combine 4-way parity group
  den += __shfl_xor(den, 1);
  den += __shfl_xor(den, 2);
#pragma unroll
  for (int c = 0; c < 10; c++) {
    acc[c] += __shfl_xor(acc[c], 1);
    acc[c] += __shfl_xor(acc[c], 2);
  }

  __syncthreads();  // xrw reads done; sXr reusable for g
  if (part == 0) {
    float inv = 1.f / (den + 1e-16f);
#pragma unroll
    for (int c = 0; c < 10; c++)
      sXr[n * 20 + head * 10 + c] = acc[c] * inv + sGb[head * 10 + c];
  }
  __syncthreads();

  // output: out[node] = g @ W34 + b34 ; 4 node-groups in parallel
  int col = t & 127, grp = t >> 7;
  for (int n2 = grp; n2 < 64; n2 += 4) {
    int gn = node0 + n2;
    if (gn >= NN) break;
    float v = sb[col];
    const float* g = &sXr[n2 * 20];
#pragma unroll
    for (int c = 0; c < 20; c++) v += g[c] * sW[c * 128 + col];
    if (f32f) ((float*)out)[(size_t)gn * 128 + col] = v;
    else ((unsigned short*)out)[(size_t)gn * 128 + col] = (unsigned short)f2bf(v);
  }
}

extern "C" void kernel_launch(void* const* d_in, const int* in_sizes, int n_in,
                              void* d_out, int out_size, void* d_ws, size_t ws_size,
                              hipStream_t stream) {
  (void)in_sizes; (void)n_in; (void)out_size; (void)ws_size;
  const void* sig  = d_in[0];
  const int*  ei   = (const int*)d_in[1];
  const void* ew   = d_in[2];
  const void* mask = d_in[3];
  const void* W1   = d_in[4];
  const void* b1   = d_in[5];
  const void* gam  = d_in[6];
  const void* bet  = d_in[7];
  const void* W2   = d_in[8];
  const void* b2   = d_in[9];
  const void* Wl   = d_in[10];
  const void* bl   = d_in[11];
  const void* Wr   = d_in[12];
  const void* br   = d_in[13];
  const void* We   = d_in[14];
  const void* att  = d_in[15];
  const void* gb   = d_in[16];
  const void* W3   = d_in[17];
  const void* b3   = d_in[18];
  const void* W4   = d_in[19];
  const void* b4   = d_in[20];

  char* ws = (char*)d_ws;
  short* W1T    = (short*)(ws + OFF_W1T);
  short* W2T    = (short*)(ws + OFF_W2T);
  float* b1eff  = (float*)(ws + OFF_B1E);
  float* smallf = (float*)(ws + OFF_SMALL);
  float* W34    = (float*)(ws + OFF_W34);
  float* b34    = (float*)(ws + OFF_B34);
  int*   flags  = (int*)(ws + OFF_FLAGS);
  unsigned short* xlb = (unsigned short*)(ws + OFF_XLB);
  float* xr     = (float*)(ws + OFF_XR);
  int*   gh     = (int*)(ws + OFF_GH);
  int*   bb     = (int*)(ws + OFF_BB);
  int*   bsum   = (int*)(ws + OFF_BS);
  int2*  bincsr = (int2*)(ws + OFF_BIN);

  kPrep<<<459, 256, 0, stream>>>(W1, b1, gam, bet, W2, b2, Wl, bl, Wr, br, We, att,
                                 gb, W3, b3, W4, b4, mask, flags,
                                 W1T, b1eff, W2T, smallf, W34, b34);
  kA<<<NBLK_A, 256, 0, stream>>>(sig, mask, W1T, b1eff, W2T, smallf, flags, xlb, xr);
  kB1<<<EBLK, 256, 0, stream>>>(ei, gh);
  kS1<<<(MSCAN + 2047) / 2048, 256, 0, stream>>>(gh, gh, bsum, MSCAN);
  kS2<<<1, 256, 0, stream>>>(bsum, (MSCAN + 2047) / 2048);
  kS3<<<NB, 256, 0, stream>>>(gh, bsum, bb);
  kB3<<<EBLK, 256, 0, stream>>>(ei, ew, flags, gh, bincsr);
  kAgg<<<NB, 512, 0, stream>>>(bb, bincsr, xlb, xr, smallf, W34, b34, flags, d_out);
}

// Round 11
// 386.587 us; speedup vs baseline: 1.3243x; 1.0468x over previous
//
#include <hip/hip_runtime.h>
#include <hip/hip_bf16.h>

// ---------------- problem constants ----------------
constexpr int NN = 100000;   // nodes
constexpr int NE = 3200000;  // edges
constexpr int CYC = 128;     // signal channels
constexpr int NB = 1563;     // buckets of 64 nodes: ceil(100000/64)
constexpr int EBLK = 256;    // edge-pass blocks
constexpr int ECHUNK = NE / EBLK;  // 12500
constexpr int CAP = 2432;    // bucket edge capacity: mean 2048 + 8.5 sigma
constexpr int NBLK_A = (NN + 63) / 64;  // 1563 row-blocks for kA (64 rows)
constexpr int NPREP = 459;   // kPrep blocks

// ---------------- workspace layout (bytes) ----------------
#define OFF_W1T    0u          // [512][128] bf16
#define OFF_W2T    131072u     // [16][512]  bf16
#define OFF_B1E    147456u     // [512] f32
#define OFF_SMALL  149504u     // 516 f32
#define OFF_W34    151808u     // [20][128] f32
#define OFF_B34    162048u     // [128] f32
#define OFF_FLAGS  162560u     // ints
#define OFF_XLB    163840u     // [N][32] bf16 (head0 @0..9, head1 @16..25) = 6,400,000
#define OFF_XR     6563840u    // [N][20] f32 = 8,000,000
#define OFF_BE     14563840u   // bend [NB] int (old NC region)
#define OFF_GH     14965248u   // [NB][EBLK] int = 1,600,512
#define OFF_BB     16565760u   // [NB+1] int (pad 6400)
#define OFF_GC     16572160u   // global alloc counter (1 int, pad 1024)
#define OFF_BIN    16573184u   // [E] int2 = 25,600,000
// total = 42,173,184 bytes (< proven 51.4 MB)

// smallf float offsets
#define SF_WLR 0
#define SF_BLR 400
#define SF_ATT 440
#define SF_WE  460
#define SF_GB  480
#define SF_B2  500

typedef __attribute__((ext_vector_type(8))) short bf16x8;
typedef __attribute__((ext_vector_type(4))) float f32x4;

__device__ __forceinline__ float bfu(unsigned short x) {
  return __uint_as_float(((unsigned)x) << 16);
}
__device__ __forceinline__ short f2bf(float f) {
  __hip_bfloat16 h = __float2bfloat16(f);
  return *reinterpret_cast<short*>(&h);
}
__device__ __forceinline__ float LD(const void* p, long i, int f32f) {
  return f32f ? ((const float*)p)[i] : bfu(((const unsigned short*)p)[i]);
}

// ---------------- F1: precompute (blocks 0..458) U bucket histogram (459..714) --
__global__ __launch_bounds__(256) void kPrepHist(
    const void* __restrict__ W1, const void* __restrict__ b1,
    const void* __restrict__ gamma, const void* __restrict__ beta,
    const void* __restrict__ W2, const void* __restrict__ b2,
    const void* __restrict__ Wl, const void* __restrict__ bl,
    const void* __restrict__ Wr, const void* __restrict__ br,
    const void* __restrict__ We, const void* __restrict__ att,
    const void* __restrict__ gbias, const void* __restrict__ W3,
    const void* __restrict__ b3, const void* __restrict__ W4,
    const void* __restrict__ b4, const void* __restrict__ mask,
    const int* __restrict__ ei,
    int* __restrict__ flags,
    short* __restrict__ W1T, float* __restrict__ b1eff, short* __restrict__ W2T,
    float* __restrict__ smallf, float* __restrict__ W34, float* __restrict__ b34,
    int* __restrict__ gh, int* __restrict__ gcnt)
{
  __shared__ int h[NB];
  __shared__ int sfl[2];
  int t = threadIdx.x;

  if (blockIdx.x >= NPREP) {
    // ---- kB1 part: per-block bucket histogram ----
    int blk = blockIdx.x - NPREP;
    for (int i = t; i < NB; i += 256) h[i] = 0;
    __syncthreads();
    const int* dst = ei + NE;
    int base = blk * ECHUNK, bend_ = base + ECHUNK;
    for (int i = base + t; i < bend_; i += 256)
      atomicAdd(&h[dst[i] >> 6], 1);
    __syncthreads();
    for (int i = t; i < NB; i += 256) gh[i * EBLK + blk] = h[i];
    return;
  }

  // ---- kPrep part ----
  if (t < 64) {
    const unsigned short* W1u = (const unsigned short*)W1;
    const unsigned* masku = (const unsigned*)mask;
    int big = 0;
#pragma unroll
    for (int k = 0; k < 8; k++) {
      unsigned e = (W1u[t * 8 + k] >> 7) & 0xFF;
      if (e >= 170) big++;
    }
    int byt = 0;
#pragma unroll
    for (int k = 0; k < 4; k++) if (masku[t * 4 + k] & ~1u) byt = 1;
#pragma unroll
    for (int o = 1; o < 64; o <<= 1) {
      big += __shfl_xor(big, o);
      byt |= __shfl_xor(byt, o);
    }
    if (t == 0) {
      sfl[0] = (big >= 4) ? 1 : 0;
      sfl[1] = byt;
      if (blockIdx.x == 0) { flags[0] = sfl[0]; flags[1] = byt; gcnt[0] = 0; }
    }
  }
  __syncthreads();
  const int f32f = sfl[0];

  int tid = blockIdx.x * 256 + t;
  const float rs = 0.999995000037f;  // 1/sqrt(1+1e-5)
  if (tid < 65536) {
    int j = tid >> 7, k = tid & 127;
    float s = LD(gamma, j, f32f) * rs;
    W1T[j * 128 + k] = f2bf(LD(W1, k * 512 + j, f32f) * s);
    if (k == 0) b1eff[j] = LD(b1, j, f32f) * s + LD(beta, j, f32f);
  } else if (tid < 73728) {
    int i = tid - 65536;
    int c = i >> 9, k = i & 511;
    W2T[c * 512 + k] = (c < 10) ? f2bf(LD(W2, k * 10 + c, f32f)) : (short)0;
  } else if (tid < 114688) {
    int i = tid - 73728;        // 16 threads per W34 output
    int o = i >> 4, k0 = i & 15;
    int j = o >> 7, tt = o & 127;
    float acc = 0.f;
    for (int k = k0; k < 512; k += 16)
      acc += LD(W3, j * 512 + k, f32f) * LD(W4, k * 128 + tt, f32f);
#pragma unroll
    for (int o2 = 1; o2 < 16; o2 <<= 1) acc += __shfl_xor(acc, o2);
    if (k0 == 0) W34[o] = acc;
  } else if (tid < 116736) {
    int i = tid - 114688;       // 16 threads per b34 output
    int tt = i >> 4, k0 = i & 15;
    float acc = 0.f;
    for (int k = k0; k < 512; k += 16)
      acc += LD(b3, k, f32f) * LD(W4, k * 128 + tt, f32f);
#pragma unroll
    for (int o2 = 1; o2 < 16; o2 <<= 1) acc += __shfl_xor(acc, o2);
    if (k0 == 0) b34[tt] = acc + LD(b4, tt, f32f);
  } else if (tid < 117252) {
    int i = tid - 116736;
    if (i < 400) {
      int c = i / 40, o = i % 40;
      smallf[SF_WLR + i] = (o < 20) ? LD(Wl, c * 20 + o, f32f) : LD(Wr, c * 20 + (o - 20), f32f);
    } else if (i < 440) {
      int o = i - 400;
      smallf[SF_BLR + o] = (o < 20) ? LD(bl, o, f32f) : LD(br, o - 20, f32f);
    } else if (i < 460) {
      smallf[SF_ATT + (i - 440)] = LD(att, i - 440, f32f);
    } else if (i < 480) {
      smallf[SF_WE + (i - 460)] = LD(We, i - 460, f32f);
    } else if (i < 500) {
      smallf[SF_GB + (i - 480)] = LD(gbias, i - 480, f32f);
    } else {
      int c = i - 500;
      smallf[SF_B2 + c] = (c < 10) ? LD(b2, c, f32f) : 0.f;
    }
  }
}

// ---------------- F2: kA (blocks 0..1562) U per-bucket scan (1563..3125) -------
// kA: round-7 proven 64-row two-half version, launch_bounds(256,2), no spill.
// kScan: one block per bucket; scans its 256 per-block counts in LDS, allocates
// the bucket's base via ONE global atomicAdd (1563 total - trivial), updates gh
// in place and emits bb/bend. Replaces the 3-kernel ordered scan (ordering of
// bucket bases is irrelevant to kAgg - only contiguity matters).
__global__ __launch_bounds__(256, 2) void kAScan(
    const void* __restrict__ sig, const void* __restrict__ mask,
    const short* __restrict__ W1T, const float* __restrict__ b1eff,
    const short* __restrict__ W2T, const float* __restrict__ smallf,
    const int* __restrict__ flags,
    unsigned short* __restrict__ xlb, float* __restrict__ xr,
    int* __restrict__ gh, int* __restrict__ bb, int* __restrict__ bend,
    int* __restrict__ gcnt)
{
  // region R1 (17408 B) is time-multiplexed: A-tile -> xhp -> xlr (barriers between)
  __shared__ __align__(16) char sR1[17408];
  __shared__ short sH[4][32 * 136];   // per-wave h1 buffer [32][136] bf16
  __shared__ float sb1[512];
  __shared__ float sxh[64][12];
  __shared__ float sWlr[400];
  __shared__ float sblr[40];
  __shared__ float sb2[16];

  short (*sA)[136]        = (short (*)[136])sR1;       // 64*136*2 = 17408
  float (*sxhp)[64][17]   = (float (*)[64][17])sR1;    // 4*64*17*4 = 17408
  float (*sxlr)[40]       = (float (*)[40])sR1;        // 64*40*4  = 10240

  int t = threadIdx.x;

  if (blockIdx.x >= NBLK_A) {
    // ---- kScan part: alias LDS onto sb1/sb2 (no LDS growth) ----
    int* sS = (int*)sb1;        // 256 ints
    int* sBase = (int*)sb2;     // 1 int
    int b = blockIdx.x - NBLK_A;
    int c = gh[b * EBLK + t];
    sS[t] = c;
    __syncthreads();
    for (int o = 1; o < 256; o <<= 1) {
      int v = (t >= o) ? sS[t - o] : 0;
      __syncthreads();
      sS[t] += v;
      __syncthreads();
    }
    if (t == 255) sBase[0] = atomicAdd(gcnt, sS[255]);
    __syncthreads();
    int base = sBase[0];
    gh[b * EBLK + t] = base + sS[t] - c;   // exclusive offset within bucket
    if (t == 255) { bb[b] = base; bend[b] = base + sS[255]; }
    return;
  }

  // ---- kA part (round-7 verbatim) ----
  const int f32f = flags[0];
  const int mk8  = flags[1];
  int w = t >> 6, l = t & 63;
  int lrow = l & 15, quad = l >> 4;
  int row0 = blockIdx.x * 64;

  for (int i = t; i < 512; i += 256) sb1[i] = b1eff[i];
  for (int i = t; i < 400; i += 256) sWlr[i] = smallf[SF_WLR + i];
  if (t < 40) sblr[t] = smallf[SF_BLR + t];
  if (t < 16) sb2[t] = smallf[SF_B2 + t];

  // ---- stage A tile: 64 rows x 128 bf16; 1024 16B-chunks, 4 per thread ----
  bf16x8 zz = {0, 0, 0, 0, 0, 0, 0, 0};
#pragma unroll
  for (int k = 0; k < 4; k++) {
    int idx = t + k * 256;
    int row = idx >> 4, seg = idx & 15;
    int gr = row0 + row;
    int grc = gr < NN ? gr : NN - 1;
    bool mbit = mk8 ? (((const unsigned char*)mask)[grc] != 0)
                    : (((const int*)mask)[grc] != 0);
    bf16x8 v;
    if (mbit) {
      v = zz;
    } else if (f32f) {
      const float4* Sf = (const float4*)((const float*)sig + (size_t)grc * CYC) + seg * 2;
      float4 x0 = Sf[0], x1 = Sf[1];
      v[0] = f2bf(x0.x); v[1] = f2bf(x0.y); v[2] = f2bf(x0.z); v[3] = f2bf(x0.w);
      v[4] = f2bf(x1.x); v[5] = f2bf(x1.y); v[6] = f2bf(x1.z); v[7] = f2bf(x1.w);
    } else {
      v = ((const bf16x8*)((const unsigned short*)sig + (size_t)grc * CYC))[seg];
    }
    *(bf16x8*)&sA[row][seg * 8] = v;
  }
  __syncthreads();

  // bias columns for this wave's 128 cols
  float bcol[8];
#pragma unroll
  for (int ct = 0; ct < 8; ct++) bcol[ct] = sb1[w * 128 + ct * 16 + lrow];

  // ---- GEMM1: 64 rows x 128 cols, K=128; 4 MFMA per bv load ----
  f32x4 acc[4][8];
#pragma unroll
  for (int rf = 0; rf < 4; rf++)
#pragma unroll
    for (int ct = 0; ct < 8; ct++) acc[rf][ct] = (f32x4){0.f, 0.f, 0.f, 0.f};

  const bf16x8* Bp = (const bf16x8*)W1T;
  int bvbase = w * 2048 + lrow * 16 + quad;
#pragma unroll
  for (int kt = 0; kt < 4; kt++) {
    bf16x8 a0 = *(const bf16x8*)&sA[lrow][kt * 32 + quad * 8];
    bf16x8 a1 = *(const bf16x8*)&sA[16 + lrow][kt * 32 + quad * 8];
    bf16x8 a2f = *(const bf16x8*)&sA[32 + lrow][kt * 32 + quad * 8];
    bf16x8 a3 = *(const bf16x8*)&sA[48 + lrow][kt * 32 + quad * 8];
#pragma unroll
    for (int ct = 0; ct < 8; ct++) {
      bf16x8 bv = Bp[bvbase + ct * 256 + kt * 4];
      acc[0][ct] = __builtin_amdgcn_mfma_f32_16x16x32_bf16(a0, bv, acc[0][ct], 0, 0, 0);
      acc[1][ct] = __builtin_amdgcn_mfma_f32_16x16x32_bf16(a1, bv, acc[1][ct], 0, 0, 0);
      acc[2][ct] = __builtin_amdgcn_mfma_f32_16x16x32_bf16(a2f, bv, acc[2][ct], 0, 0, 0);
      acc[3][ct] = __builtin_amdgcn_mfma_f32_16x16x32_bf16(a3, bv, acc[3][ct], 0, 0, 0);
    }
  }
  __syncthreads();   // all waves done reading sA -> R1 region free for xhp

  // GEMM2 B-operand (W2T) fragments, reused across both halves
  const bf16x8* B2p = (const bf16x8*)W2T;
  bf16x8 b2v[4];
#pragma unroll
  for (int kt2 = 0; kt2 < 4; kt2++) b2v[kt2] = B2p[lrow * 64 + w * 16 + kt2 * 4 + quad];

  short* hb = &sH[w][0];   // per-wave [32][136]
#pragma unroll
  for (int hf = 0; hf < 2; hf++) {
    // write h1 half (rows hf*32 .. hf*32+31) with bias + relu, bf16
#pragma unroll
    for (int rr = 0; rr < 2; rr++) {
      int rf = hf * 2 + rr;
#pragma unroll
      for (int ct = 0; ct < 8; ct++) {
        float bb_ = bcol[ct];
#pragma unroll
        for (int r = 0; r < 4; r++) {
          float vv = fmaxf(acc[rf][ct][r] + bb_, 0.f);
          hb[(rr * 16 + quad * 4 + r) * 136 + ct * 16 + lrow] = f2bf(vv);
        }
      }
    }
    // wave-local fence: all our LDS writes retired before any lane reads them
    asm volatile("s_waitcnt lgkmcnt(0)" ::: "memory");

    // GEMM2 on this half: h1[32][128] @ W2T -> xh partial [32][16]
    f32x4 a2[2];
    a2[0] = (f32x4){0.f, 0.f, 0.f, 0.f};
    a2[1] = (f32x4){0.f, 0.f, 0.f, 0.f};
#pragma unroll
    for (int kt2 = 0; kt2 < 4; kt2++) {
      bf16x8 x0 = *(const bf16x8*)&hb[lrow * 136 + kt2 * 32 + quad * 8];
      bf16x8 x1 = *(const bf16x8*)&hb[(16 + lrow) * 136 + kt2 * 32 + quad * 8];
      a2[0] = __builtin_amdgcn_mfma_f32_16x16x32_bf16(x0, b2v[kt2], a2[0], 0, 0, 0);
      a2[1] = __builtin_amdgcn_mfma_f32_16x16x32_bf16(x1, b2v[kt2], a2[1], 0, 0, 0);
    }
#pragma unroll
    for (int f = 0; f < 2; f++)
#pragma unroll
      for (int r = 0; r < 4; r++)
        sxhp[w][hf * 32 + f * 16 + quad * 4 + r][lrow] = a2[f][r];
  }
  __syncthreads();

  // reduce 4 wave-partials -> xh[64][10] (+b2)
  for (int i = t; i < 640; i += 256) {
    int row = i / 10, c = i - row * 10;
    sxh[row][c] = sxhp[0][row][c] + sxhp[1][row][c] + sxhp[2][row][c] + sxhp[3][row][c] + sb2[c];
  }
  __syncthreads();

  // xl/xr into LDS staging (overlay on R1)
  for (int i = t; i < 2560; i += 256) {
    int row = i / 40, o = i - row * 40;
    float v = sblr[o];
#pragma unroll
    for (int c = 0; c < 10; c++) v += sxh[row][c] * sWlr[c * 40 + o];
    sxlr[row][o] = v;
  }
  __syncthreads();

  // coalesced stores
  int nrows = NN - row0; if (nrows > 64) nrows = 64;
  unsigned* xlb32 = (unsigned*)xlb;
#pragma unroll
  for (int k = 0; k < 4; k++) {
    int i = t + k * 256;
    int row = i >> 4, p = i & 15;
    if (row < nrows) {
      int s0 = 2 * p, s1 = 2 * p + 1;
      float lo = (s0 < 10) ? sxlr[row][s0] : (s0 >= 16 && s0 < 26) ? sxlr[row][s0 - 6] : 0.f;
      float hi = (s1 < 10) ? sxlr[row][s1] : (s1 >= 16 && s1 < 26) ? sxlr[row][s1 - 6] : 0.f;
      unsigned u = (unsigned)(unsigned short)f2bf(lo) |
                   ((unsigned)(unsigned short)f2bf(hi) << 16);
      xlb32[(size_t)(row0 + row) * 16 + p] = u;
    }
  }
#pragma unroll
  for (int k = 0; k < 5; k++) {
    int i = t + k * 256;
    int row = i / 20, c = i - row * 20;
    if (row < nrows) xr[(size_t)(row0 + row) * 20 + c] = sxlr[row][20 + c];
  }
}

// ---------------- bin edges by 64-node bucket (locality-friendly scatter) ------
__global__ __launch_bounds__(256) void kB3(const int* __restrict__ ei,
                                           const void* __restrict__ ew,
                                           const int* __restrict__ flags,
                                           const int* __restrict__ gh,
                                           int2* __restrict__ binned) {
  __shared__ int cur[NB];
  const int f32f = flags[0];
  int t = threadIdx.x, blk = blockIdx.x;
  for (int i = t; i < NB; i += 256) cur[i] = gh[i * EBLK + blk];
  __syncthreads();
  int base = blk * ECHUNK, bend_ = base + ECHUNK;
  for (int i = base + t; i < bend_; i += 256) {
    int s = ei[i], d = ei[NE + i];
    float w = LD(ew, i, f32f);
    int b = d >> 6;
    int pos = atomicAdd(&cur[b], 1);
    binned[pos] = make_int2(s | ((d & 63) << 17), __float_as_int(w));
  }
}

// ---------------- fused per-bucket sort + aggregate + output GEMM ----------------
// one block per 64-node bucket; 512 threads; LDS counting sort (count from
// global, scatter via L2-hot re-read into sES); 8 threads/node (2 head x 4 par).
__global__ __launch_bounds__(512) void kAgg(
    const int* __restrict__ bb, const int* __restrict__ bend,
    const int2* __restrict__ binned,
    const unsigned short* __restrict__ xlb, const float* __restrict__ xr,
    const float* __restrict__ smallf, const float* __restrict__ W34,
    const float* __restrict__ b34, const int* __restrict__ flags,
    void* __restrict__ out)
{
  __shared__ int2  sES[CAP];        // 19,456 B (bucket edges, node-sorted)
  __shared__ float sXr[64 * 20];    // xr rows; reused for g after aggregate
  __shared__ float sW[2560];
  __shared__ float sb[128];
  __shared__ int   sCnt[64], sPre[64], sStart[64], sCur[64];
  __shared__ float sAtt[20], sWe[20], sGb[20];

  const int f32f = flags[0];
  int t = threadIdx.x, b = blockIdx.x;
  int node0 = b * 64;

  for (int i = t; i < 2560; i += 512) sW[i] = W34[i];
  for (int i = t; i < 1280; i += 512) {
    int gi = node0 * 20 + i;
    sXr[i] = (gi < NN * 20) ? xr[gi] : 0.f;
  }
  if (t < 128) sb[t] = b34[t];
  if (t < 64) sCnt[t] = 0;
  if (t < 20) { sAtt[t] = smallf[SF_ATT + t]; sWe[t] = smallf[SF_WE + t]; sGb[t] = smallf[SF_GB + t]; }
  __syncthreads();

  int base = bb[b], end = bend[b];
  int ne = end - base;

  // pass 1: count per local node
  for (int i = t; i < ne; i += 512)
    atomicAdd(&sCnt[(unsigned)binned[base + i].x >> 17], 1);
  __syncthreads();

  // 64-wide exclusive prefix
  if (t < 64) sPre[t] = sCnt[t];
  __syncthreads();
  for (int o = 1; o < 64; o <<= 1) {
    int v = 0;
    if (t < 64 && t >= o) v = sPre[t - o];
    __syncthreads();
    if (t < 64) sPre[t] += v;
    __syncthreads();
  }
  if (t < 64) {
    int ex = sPre[t] - sCnt[t];
    sStart[t] = ex;
    sCur[t] = ex;
  }
  __syncthreads();

  // pass 2: scatter into node-sorted LDS order (re-read is L2-hot)
  for (int i = t; i < ne; i += 512) {
    int2 e = binned[base + i];
    int dl = (unsigned)e.x >> 17;
    int pos = atomicAdd(&sCur[dl], 1);
    if (pos < CAP) sES[pos] = make_int2(e.x & 0x1FFFF, e.y);
  }
  __syncthreads();

  // aggregate: 8 threads/node = (head, 4-way parity)
  int n = t >> 3, sub = t & 7, head = sub >> 2, part = sub & 3;
  float xrw[10], attw[10], wew[10];
#pragma unroll
  for (int c = 0; c < 10; c++) {
    xrw[c]  = sXr[n * 20 + head * 10 + c];
    attw[c] = sAtt[head * 10 + c];
    wew[c]  = sWe[head * 10 + c];
  }
  float acc[10];
#pragma unroll
  for (int c = 0; c < 10; c++) acc[c] = 0.f;
  float den = 0.f;
  int s0 = sStart[n];
  int s1 = s0 + sCnt[n];
  if (s1 > CAP) s1 = CAP;  // statistically unreachable

  // 1-deep software pipeline on the xlb gather (edge records are LDS-fast)
  int i = s0 + part;
  int2 e; uint4 q; unsigned q4;
  if (i < s1) {
    e = sES[i];
    const unsigned short* p = xlb + (size_t)e.x * 32 + head * 16;
    q = *(const uint4*)p;
    q4 = *(const unsigned*)(p + 8);
  }
  while (i < s1) {
    int j = i + 4;
    int2 en; uint4 qn; unsigned qn4;
    if (j < s1) {
      en = sES[j];
      const unsigned short* pn = xlb + (size_t)en.x * 32 + head * 16;
      qn = *(const uint4*)pn;
      qn4 = *(const unsigned*)(pn + 8);
    }
    float vl[10];
    unsigned qq[5] = {q.x, q.y, q.z, q.w, q4};
#pragma unroll
    for (int k = 0; k < 5; k++) {
      vl[2 * k]     = __uint_as_float(qq[k] << 16);
      vl[2 * k + 1] = __uint_as_float(qq[k] & 0xffff0000u);
    }
    float ww = __int_as_float(e.y);
    float a = 0.f;
#pragma unroll
    for (int c = 0; c < 10; c++) {
      float v = vl[c] + xrw[c] + ww * wew[c];
      v = fmaxf(v, 0.2f * v);  // leaky_relu(0.2)
      a += v * attw[c];
    }
    float pp = __expf(a);
    den += pp;
#pragma unroll
    for (int c = 0; c < 10; c++) acc[c] += pp * vl[c];
    e = en; q = qn; q4 = qn4; i = j;
  }
  // combine 4-way parity group
  den += __shfl_xor(den, 1);
  den += __shfl_xor(den, 2);
#pragma unroll
  for (int c = 0; c < 10; c++) {
    acc[c] += __shfl_xor(acc[c], 1);
    acc[c] += __shfl_xor(acc[c], 2);
  }

  __syncthreads();  // xrw reads done; sXr reusable for g
  if (part == 0) {
    float inv = 1.f / (den + 1e-16f);
#pragma unroll
    for (int c = 0; c < 10; c++)
      sXr[n * 20 + head * 10 + c] = acc[c] * inv + sGb[head * 10 + c];
  }
  __syncthreads();

  // output: out[node] = g @ W34 + b34 ; 4 node-groups in parallel
  int col = t & 127, grp = t >> 7;
  for (int n2 = grp; n2 < 64; n2 += 4) {
    int gn = node0 + n2;
    if (gn >= NN) break;
    float v = sb[col];
    const float* g = &sXr[n2 * 20];
#pragma unroll
    for (int c = 0; c < 20; c++) v += g[c] * sW[c * 128 + col];
    if (f32f) ((float*)out)[(size_t)gn * 128 + col] = v;
    else ((unsigned short*)out)[(size_t)gn * 128 + col] = (unsigned short)f2bf(v);
  }
}

extern "C" void kernel_launch(void* const* d_in, const int* in_sizes, int n_in,
                              void* d_out, int out_size, void* d_ws, size_t ws_size,
                              hipStream_t stream) {
  (void)in_sizes; (void)n_in; (void)out_size; (void)ws_size;
  const void* sig  = d_in[0];
  const int*  ei   = (const int*)d_in[1];
  const void* ew   = d_in[2];
  const void* mask = d_in[3];
  const void* W1   = d_in[4];
  const void* b1   = d_in[5];
  const void* gam  = d_in[6];
  const void* bet  = d_in[7];
  const void* W2   = d_in[8];
  const void* b2   = d_in[9];
  const void* Wl   = d_in[10];
  const void* bl   = d_in[11];
  const void* Wr   = d_in[12];
  const void* br   = d_in[13];
  const void* We   = d_in[14];
  const void* att  = d_in[15];
  const void* gb   = d_in[16];
  const void* W3   = d_in[17];
  const void* b3   = d_in[18];
  const void* W4   = d_in[19];
  const void* b4   = d_in[20];

  char* ws = (char*)d_ws;
  short* W1T    = (short*)(ws + OFF_W1T);
  short* W2T    = (short*)(ws + OFF_W2T);
  float* b1eff  = (float*)(ws + OFF_B1E);
  float* smallf = (float*)(ws + OFF_SMALL);
  float* W34    = (float*)(ws + OFF_W34);
  float* b34    = (float*)(ws + OFF_B34);
  int*   flags  = (int*)(ws + OFF_FLAGS);
  unsigned short* xlb = (unsigned short*)(ws + OFF_XLB);
  float* xr     = (float*)(ws + OFF_XR);
  int*   bendp  = (int*)(ws + OFF_BE);
  int*   gh     = (int*)(ws + OFF_GH);
  int*   bb     = (int*)(ws + OFF_BB);
  int*   gcnt   = (int*)(ws + OFF_GC);
  int2*  bincsr = (int2*)(ws + OFF_BIN);

  kPrepHist<<<NPREP + EBLK, 256, 0, stream>>>(
      W1, b1, gam, bet, W2, b2, Wl, bl, Wr, br, We, att, gb, W3, b3, W4, b4,
      mask, ei, flags, W1T, b1eff, W2T, smallf, W34, b34, gh, gcnt);
  kAScan<<<NBLK_A + NB, 256, 0, stream>>>(
      sig, mask, W1T, b1eff, W2T, smallf, flags, xlb, xr, gh, bb, bendp, gcnt);
  kB3<<<EBLK, 256, 0, stream>>>(ei, ew, flags, gh, bincsr);
  kAgg<<<NB, 512, 0, stream>>>(bb, bendp, bincsr, xlb, xr, smallf, W34, b34, flags, d_out);
}